// Round 1
// baseline (118.724 us; speedup 1.0000x reference)
//
#include <hip/hip_runtime.h>
#include <math.h>

#define KM 192
#define EPSF 1e-6f
#define QMIN 0.5f

__device__ __forceinline__ float clipb(float b) {
    return fminf(fmaxf(b, 1e-4f), 1.0f - 1e-4f);
}

// ---------------- zero workspace ----------------
__global__ void k_zero(unsigned int* p, int n) {
    int i = blockIdx.x * blockDim.x + threadIdx.x;
    if (i < n) p[i] = 0u;
}

// ---------------- per-object argmax of q (packed u64 atomicMax) ----------------
__global__ void k_argmax(const float* __restrict__ beta, const int* __restrict__ tidx,
                         unsigned long long* __restrict__ packs, int N) {
    const int e = blockIdx.y;
    __shared__ unsigned long long smax[KM];
    for (int k = threadIdx.x; k < KM; k += blockDim.x) smax[k] = 0ull;
    __syncthreads();

    const float* b = beta + (size_t)e * N;
    const int*   t = tidx + (size_t)e * N;
    const int stride = gridDim.x * blockDim.x;
    for (int i = blockIdx.x * blockDim.x + threadIdx.x; i < N; i += stride) {
        int k = t[i];
        if (k > 0) {
            float bc = clipb(b[i]);
            float a  = atanhf(bc);
            float q  = a * a + QMIN;
            // q > 0 => float bits monotone; low word (N-1-i) reproduces argmax first-index tiebreak
            unsigned long long pack =
                ((unsigned long long)__float_as_uint(q) << 32) |
                (unsigned long long)(unsigned)(N - 1 - i);
            atomicMax(&smax[k], pack);
        }
    }
    __syncthreads();
    for (int k = threadIdx.x; k < KM; k += blockDim.x)
        if (smax[k]) atomicMax(&packs[e * KM + k], smax[k]);
}

// ---------------- gather alpha-point data, per-event L_beta / n_obj ----------------
__global__ void k_gather(const float* __restrict__ beta, const float* __restrict__ cc,
                         const unsigned long long* __restrict__ packs,
                         float* __restrict__ xa0, float* __restrict__ xa1,
                         float* __restrict__ qv,  float* __restrict__ vf,
                         float* __restrict__ scal, int N) {
    const int e = blockIdx.x;
    const int k = threadIdx.x;                 // blockDim = 256, slots 0..191 active
    float lb = 0.f, nv = 0.f;
    if (k < KM) {
        unsigned long long p = packs[e * KM + k];
        float x0 = 0.f, x1 = 0.f, q = 0.f, v = 0.f;
        if (p) {
            int idx = N - 1 - (int)(unsigned)(p & 0xffffffffull);
            q  = __uint_as_float((unsigned)(p >> 32));
            x0 = cc[((size_t)e * N + idx) * 2 + 0];
            x1 = cc[((size_t)e * N + idx) * 2 + 1];
            float bc = clipb(beta[(size_t)e * N + idx]);
            lb = 1.0f - bc;
            v = 1.f; nv = 1.f;
        }
        xa0[e * KM + k] = x0;
        xa1[e * KM + k] = x1;
        qv [e * KM + k] = q * v;               // q_alpha * valid (masked)
        vf [e * KM + k] = v;
    }
    __shared__ float r1[256], r2[256];
    r1[threadIdx.x] = lb; r2[threadIdx.x] = nv;
    __syncthreads();
    for (int s = 128; s > 0; s >>= 1) {
        if (threadIdx.x < s) { r1[threadIdx.x] += r1[threadIdx.x + s];
                               r2[threadIdx.x] += r2[threadIdx.x + s]; }
        __syncthreads();
    }
    if (threadIdx.x == 0) { scal[e * 8 + 1] = r1[0];   // L_beta numerator
                            scal[e * 8 + 2] = r2[0]; } // n_obj (pre-eps)
}

// ---------------- main per-hit pass: L_V, noise, energy accumulators ----------------
__global__ void k_main(const float* __restrict__ beta, const float* __restrict__ cc,
                       const float* __restrict__ pe,   const float* __restrict__ te,
                       const int* __restrict__ tidx,
                       const float* __restrict__ xa0, const float* __restrict__ xa1,
                       const float* __restrict__ qv,
                       float* __restrict__ enum_, float* __restrict__ eden,
                       float* __restrict__ scal, int N) {
    const int e = blockIdx.y;
    __shared__ float s0[KM], s1[KM], sq[KM];
    __shared__ float sn[KM], sd[KM];
    for (int k = threadIdx.x; k < KM; k += blockDim.x) {
        s0[k] = xa0[e * KM + k];
        s1[k] = xa1[e * KM + k];
        sq[k] = qv [e * KM + k];
        sn[k] = 0.f; sd[k] = 0.f;
    }
    __syncthreads();

    float lv = 0.f, bn = 0.f, cn = 0.f;
    const size_t base = (size_t)e * N;
    const int stride = gridDim.x * blockDim.x;
    for (int i = blockIdx.x * blockDim.x + threadIdx.x; i < N; i += stride) {
        float bc = clipb(beta[base + i]);
        float a  = atanhf(bc);
        float q  = a * a + QMIN;
        float cx = cc[(base + i) * 2 + 0];
        float cy = cc[(base + i) * 2 + 1];
        int   t  = tidx[base + i];

        // repulsive hinge over ALL valid objects (qv already masked by validity)
        float rep = 0.f;
        #pragma unroll 8
        for (int k = 0; k < KM; ++k) {
            float dx = cx - s0[k], dy = cy - s1[k];
            float d2 = dx * dx + dy * dy;
            float w  = 1.0f - sqrtf(d2 + EPSF);
            rep += fmaxf(w, 0.f) * sq[k];
        }

        float att = 0.f;
        if (t > 0) {
            // member: attractive term + remove own-object term from rep
            float dx = cx - s0[t], dy = cy - s1[t];
            float d2 = dx * dx + dy * dy;
            att = d2 * sq[t];
            rep -= fmaxf(1.0f - sqrtf(d2 + EPSF), 0.f) * sq[t];

            // energy payload (beta-weighted Huber of relative error)
            float edv = (pe[base + i] - te[base + i]) / (te[base + i] + 1.0f);
            float ad  = fabsf(edv);
            float eh  = (ad <= 2.0f) ? 0.5f * ad * ad : 2.0f * (ad - 1.0f);
            atomicAdd(&sn[t], bc * eh);
            atomicAdd(&sd[t], bc);
        } else {
            bn += bc; cn += 1.f;
        }
        lv += q * (att + rep);
    }
    __syncthreads();

    for (int k = threadIdx.x; k < KM; k += blockDim.x) {
        if (sn[k] != 0.f) atomicAdd(&enum_[e * KM + k], sn[k]);
        if (sd[k] != 0.f) atomicAdd(&eden[e * KM + k], sd[k]);
    }

    __shared__ float ra[256], rb[256], rc[256];
    ra[threadIdx.x] = lv; rb[threadIdx.x] = bn; rc[threadIdx.x] = cn;
    __syncthreads();
    for (int s = 128; s > 0; s >>= 1) {
        if (threadIdx.x < s) { ra[threadIdx.x] += ra[threadIdx.x + s];
                               rb[threadIdx.x] += rb[threadIdx.x + s];
                               rc[threadIdx.x] += rc[threadIdx.x + s]; }
        __syncthreads();
    }
    if (threadIdx.x == 0) {
        atomicAdd(&scal[e * 8 + 0], ra[0]);   // sum q*(att+rep)
        atomicAdd(&scal[e * 8 + 3], rb[0]);   // sum beta*noise
        atomicAdd(&scal[e * 8 + 4], rc[0]);   // noise count
    }
}

// ---------------- finalize: combine losses, mean over events ----------------
__global__ void k_fin(const float* __restrict__ enum_, const float* __restrict__ eden,
                      const float* __restrict__ vf,    const float* __restrict__ scal,
                      float* __restrict__ out, int B, int N) {
    __shared__ float r[256];
    float tot = 0.f;
    for (int e = 0; e < B; ++e) {
        float le = 0.f;
        for (int k = threadIdx.x; k < KM; k += blockDim.x)
            le += vf[e * KM + k] * enum_[e * KM + k] / (eden[e * KM + k] + EPSF);
        r[threadIdx.x] = le;
        __syncthreads();
        for (int s = 128; s > 0; s >>= 1) {
            if (threadIdx.x < s) r[threadIdx.x] += r[threadIdx.x + s];
            __syncthreads();
        }
        if (threadIdx.x == 0) {
            float nobj = scal[e * 8 + 2] + EPSF;
            float LV = scal[e * 8 + 0] / (float)N;
            float LB = scal[e * 8 + 1] / nobj;
            float LN = scal[e * 8 + 3] / (scal[e * 8 + 4] + EPSF);
            float LE = r[0] / nobj;
            tot += LV + LB + LN + LE;
        }
        __syncthreads();
    }
    if (threadIdx.x == 0) out[0] = tot / (float)B;
}

extern "C" void kernel_launch(void* const* d_in, const int* in_sizes, int n_in,
                              void* d_out, int out_size, void* d_ws, size_t ws_size,
                              hipStream_t stream) {
    const int B = 4;
    const int N = in_sizes[0] / B;   // beta is [B,N,1]

    const float* beta = (const float*)d_in[0];
    const float* cc   = (const float*)d_in[1];
    const float* pe   = (const float*)d_in[2];
    const float* te   = (const float*)d_in[3];
    const int*   tidx = (const int*)  d_in[4];
    float* out = (float*)d_out;

    // workspace layout (u64 packs first for alignment)
    char* ws = (char*)d_ws;
    unsigned long long* packs = (unsigned long long*)ws;        // B*KM u64
    float* xa0  = (float*)(ws + (size_t)B * KM * 8);
    float* xa1  = xa0  + B * KM;
    float* qv   = xa1  + B * KM;
    float* vf   = qv   + B * KM;
    float* enm  = vf   + B * KM;
    float* eden = enm  + B * KM;
    float* scal = eden + B * KM;                                // B*8 floats
    const int totalWords = (B * KM * 8) / 4 + B * KM * 6 + B * 8;

    k_zero<<<dim3((totalWords + 255) / 256), dim3(256), 0, stream>>>((unsigned int*)ws, totalWords);
    k_argmax<<<dim3(64, B), dim3(256), 0, stream>>>(beta, tidx, packs, N);
    k_gather<<<dim3(B), dim3(256), 0, stream>>>(beta, cc, packs, xa0, xa1, qv, vf, scal, N);
    k_main<<<dim3(128, B), dim3(256), 0, stream>>>(beta, cc, pe, te, tidx, xa0, xa1, qv, enm, eden, scal, N);
    k_fin<<<dim3(1), dim3(256), 0, stream>>>(enm, eden, vf, scal, out, B, N);
}